// Round 12
// baseline (173.346 us; speedup 1.0000x reference)
//
#include <hip/hip_runtime.h>
#include <math.h>

#define NB   16
#define DIN  1024
#define TT   4096
#define DC   8
#define NK   1024
#define TA   128
#define NTA  (TT/TA)      // 32
#define NPG  16
#define KCP  (NK/NPG)     // 64

// d_out offsets (floats), in reference return order
#define OFF_CL  ((size_t)NB*DIN*TT)
#define OFF_CB  (OFF_CL + NB)
#define OFF_IDX (OFF_CB + NB)
#define OFF_ZE  (OFF_IDX + (size_t)NB*TT)

// ---------------- MEGA: in_proj -> VQ -> rotation -> out_proj, one block per (b, t-tile) ----------------
__global__ __launch_bounds__(512, 4) void vq_mega(const float* __restrict__ z,
    const float* __restrict__ in_w, const float* __restrict__ in_b,
    const float* __restrict__ out_w, const float* __restrict__ out_b,
    const float* __restrict__ cbk, float* __restrict__ dout,
    float* __restrict__ lpart)
{
  __shared__ float regA[DIN*DC];   // 32 KB: wt[d][o] -> cn[k][i] -> wo[o][c]
  __shared__ float regB[4*TA*DC];  // 16 KB: pacc[sub][t][o] -> cand[pg][t] (float2)
  __shared__ float ze_s[DC*TA];    //  4 KB [o][t]
  __shared__ float zq_s[DC*TA];    //  4 KB [c][t]
  __shared__ float cn2[NK];        //  4 KB
  __shared__ float obs[DIN];       //  4 KB
  __shared__ float lred[TA];       // 512 B

  const int tid = threadIdx.x;
  const int tb = blockIdx.x, b = blockIdx.y;
  const int t0 = tb*TA;

  // ======== P1: in_proj (round-10 verbatim: 512 threads, 4 subs x 128 lanes, 1 t/thread) ========
  for (int i = tid; i < DIN*DC; i += 512) {
    const int d = i >> 3, o = i & 7;
    regA[i] = in_w[o*DIN + d];
  }
  __syncthreads();
  const int sub = tid >> 7, tl = tid & 127;
  {
    const int dbase = sub*256;
    const float* zp = z + ((size_t)b*DIN + dbase)*TT + t0 + tl;
    float acc[DC];
    #pragma unroll
    for (int o = 0; o < DC; ++o) acc[o] = 0.f;
    #pragma unroll 8
    for (int d = 0; d < 256; ++d) {
      const float v = zp[(size_t)d*TT];
      const float4 w0 = *(const float4*)&regA[(dbase+d)*DC];
      const float4 w1 = *(const float4*)&regA[(dbase+d)*DC+4];
      acc[0] = fmaf(v, w0.x, acc[0]);
      acc[1] = fmaf(v, w0.y, acc[1]);
      acc[2] = fmaf(v, w0.z, acc[2]);
      acc[3] = fmaf(v, w0.w, acc[3]);
      acc[4] = fmaf(v, w1.x, acc[4]);
      acc[5] = fmaf(v, w1.y, acc[5]);
      acc[6] = fmaf(v, w1.z, acc[6]);
      acc[7] = fmaf(v, w1.w, acc[7]);
    }
    float* pa = &regB[(sub*TA + tl)*DC];
    *(float4*)&pa[0] = make_float4(acc[0], acc[1], acc[2], acc[3]);
    *(float4*)&pa[4] = make_float4(acc[4], acc[5], acc[6], acc[7]);
  }
  __syncthreads();
  #pragma unroll
  for (int oo = 0; oo < 2; ++oo) {
    const int o = sub + oo*4;
    float s = regB[(0*TA + tl)*DC + o];
    s += regB[(1*TA + tl)*DC + o];
    s += regB[(2*TA + tl)*DC + o];
    s += regB[(3*TA + tl)*DC + o];
    const float v = s + in_b[o];
    ze_s[o*TA + tl] = v;
    dout[OFF_ZE + ((size_t)b*DC + o)*TT + t0 + tl] = v;
  }
  __syncthreads();

  // ======== P2: stage+normalize codebook into regA (round-1 chain) ========
  for (int k = tid; k < NK; k += 512) {
    float c[DC];
    const float4 c0 = *(const float4*)&cbk[k*DC];
    const float4 c1 = *(const float4*)&cbk[k*DC+4];
    c[0]=c0.x; c[1]=c0.y; c[2]=c0.z; c[3]=c0.w;
    c[4]=c1.x; c[5]=c1.y; c[6]=c1.z; c[7]=c1.w;
    float ss = 0.f;
    #pragma unroll
    for (int i = 0; i < DC; ++i) ss = fmaf(c[i], c[i], ss);
    const float den = fmaxf(sqrtf(ss), 1e-12f);
    float s2 = 0.f;
    #pragma unroll
    for (int i = 0; i < DC; ++i) { const float v = c[i]/den; regA[k*DC+i] = v; s2 = fmaf(v, v, s2); }
    cn2[k] = s2;
  }
  __syncthreads();

  // scan: 16 partitions x 32 lanes, 4 t/thread (round-10 verbatim)
  {
    const int pg = tid >> 5, l = tid & 31;
    const int k0 = pg*KCP;
    float en[4][DC], en2v[4];
    #pragma unroll
    for (int m = 0; m < 4; ++m) {
      const int t = l + 32*m;
      float e[DC];
      #pragma unroll
      for (int o = 0; o < DC; ++o) e[o] = ze_s[o*TA + t];
      float se = 0.f;
      #pragma unroll
      for (int i = 0; i < DC; ++i) se = fmaf(e[i], e[i], se);
      const float dene = fmaxf(sqrtf(se), 1e-12f);
      float s2 = 0.f;
      #pragma unroll
      for (int i = 0; i < DC; ++i) { en[m][i] = e[i]/dene; s2 = fmaf(en[m][i], en[m][i], s2); }
      en2v[m] = s2;
    }
    float bd[4]; int bk[4];
    #pragma unroll
    for (int m = 0; m < 4; ++m) { bd[m] = 3.4e38f; bk[m] = k0; }
    #pragma unroll 2
    for (int k = 0; k < KCP; ++k) {
      const float4 a0 = *(const float4*)&regA[(k0+k)*DC];
      const float4 a1 = *(const float4*)&regA[(k0+k)*DC+4];
      const float c2 = cn2[k0+k];
      #pragma unroll
      for (int m = 0; m < 4; ++m) {
        float dacc = en[m][0]*a0.x;
        dacc = fmaf(en[m][1], a0.y, dacc);
        dacc = fmaf(en[m][2], a0.z, dacc);
        dacc = fmaf(en[m][3], a0.w, dacc);
        dacc = fmaf(en[m][4], a1.x, dacc);
        dacc = fmaf(en[m][5], a1.y, dacc);
        dacc = fmaf(en[m][6], a1.z, dacc);
        dacc = fmaf(en[m][7], a1.w, dacc);
        const float dist = (en2v[m] - 2.0f*dacc) + c2;   // exact round-1 chain
        if (dist < bd[m]) { bd[m] = dist; bk[m] = k0 + k; }
      }
    }
    float2* cand = (float2*)regB;   // pacc dead; cand[pg][t]
    #pragma unroll
    for (int m = 0; m < 4; ++m)
      cand[pg*TA + l + 32*m] = make_float2(bd[m], __int_as_float(bk[m]));
  }
  __syncthreads();

  // merge + rotation (lanes < 128) overlapped with out_w staging (lanes >= 128)
  if (tid < TA) {
    const float2* cand = (const float2*)regB;
    float bdm = cand[tid].x;
    int bkm = __float_as_int(cand[tid].y);
    #pragma unroll
    for (int p = 1; p < NPG; ++p) {
      const float2 c = cand[p*TA + tid];
      if (c.x < bdm) { bdm = c.x; bkm = __float_as_int(c.y); }   // ascending p => first occurrence
    }
    dout[OFF_IDX + (size_t)b*TT + t0 + tid] = (float)bkm;

    float e[DC], en_[DC];
    #pragma unroll
    for (int o = 0; o < DC; ++o) e[o] = ze_s[o*TA + tid];
    float se = 0.f;
    #pragma unroll
    for (int i = 0; i < DC; ++i) se = fmaf(e[i], e[i], se);
    const float ne = sqrtf(se);
    const float dene = fmaxf(ne, 1e-12f);
    #pragma unroll
    for (int i = 0; i < DC; ++i) en_[i] = e[i]/dene;

    float q[DC];
    {
      const float4 q0 = *(const float4*)&cbk[bkm*DC];
      const float4 q1 = *(const float4*)&cbk[bkm*DC+4];
      q[0]=q0.x; q[1]=q0.y; q[2]=q0.z; q[3]=q0.w;
      q[4]=q1.x; q[5]=q1.y; q[6]=q1.z; q[7]=q1.w;
    }
    float cl = 0.f;
    #pragma unroll
    for (int i = 0; i < DC; ++i) { const float d = e[i]-q[i]; cl = fmaf(d, d, cl); }

    float sq = 0.f;
    #pragma unroll
    for (int i = 0; i < DC; ++i) sq = fmaf(q[i], q[i], sq);
    const float nq = sqrtf(sq);
    const float denq = fmaxf(nq, 1e-12f);
    float qn[DC], rr[DC];
    float sr = 0.f;
    #pragma unroll
    for (int i = 0; i < DC; ++i) { qn[i] = q[i]/denq; rr[i] = en_[i]+qn[i]; sr = fmaf(rr[i], rr[i], sr); }
    const float denr = fmaxf(sqrtf(sr), 1e-12f);
    float r_[DC];
    float rdz = 0.f, edz = 0.f;
    #pragma unroll
    for (int i = 0; i < DC; ++i) { r_[i] = rr[i]/denr; rdz = fmaf(r_[i], e[i], rdz); edz = fmaf(en_[i], e[i], edz); }
    const float scal = nq / fmaxf(ne, 1e-8f);
    #pragma unroll
    for (int i = 0; i < DC; ++i) {
      const float v = scal * ((e[i] - 2.0f*r_[i]*rdz) + 2.0f*qn[i]*edz);
      zq_s[i*TA + tid] = v;
    }
    lred[tid] = cl;
  } else {
    const int ti = tid - TA;   // 384 stagers
    for (int i = ti; i < DIN*DC; i += 512-TA) regA[i] = out_w[i];
    for (int i = ti; i < DIN; i += 512-TA) obs[i] = out_b[i];
  }
  __syncthreads();
  for (int s = TA/2; s > 0; s >>= 1) {
    if (tid < s) lred[tid] += lred[tid + s];
    __syncthreads();
  }
  if (tid == 0) lpart[b*NTA + tb] = lred[0];

  // ======== P3: out_proj — 16 o-chunks x 32 lanes, 4 t/thread, float4 stores ========
  {
    const int oc = tid >> 5, l = tid & 31;
    const int obase = oc*64;
    const int t2 = l*4;
    float z0[DC], z1[DC], z2[DC], z3[DC];
    #pragma unroll
    for (int c = 0; c < DC; ++c) {
      const float4 v = *(const float4*)&zq_s[c*TA + t2];
      z0[c]=v.x; z1[c]=v.y; z2[c]=v.z; z3[c]=v.w;
    }
    float* op = dout + ((size_t)b*DIN + obase)*TT + t0 + t2;
    #pragma unroll 4
    for (int o = 0; o < 64; ++o) {
      const float4 w0 = *(const float4*)&regA[(obase+o)*DC];
      const float4 w1 = *(const float4*)&regA[(obase+o)*DC+4];
      const float bv = obs[obase+o];
      float s0 = bv, s1 = bv, s2 = bv, s3 = bv;
      s0 = fmaf(z0[0], w0.x, s0); s1 = fmaf(z1[0], w0.x, s1); s2 = fmaf(z2[0], w0.x, s2); s3 = fmaf(z3[0], w0.x, s3);
      s0 = fmaf(z0[1], w0.y, s0); s1 = fmaf(z1[1], w0.y, s1); s2 = fmaf(z2[1], w0.y, s2); s3 = fmaf(z3[1], w0.y, s3);
      s0 = fmaf(z0[2], w0.z, s0); s1 = fmaf(z1[2], w0.z, s1); s2 = fmaf(z2[2], w0.z, s2); s3 = fmaf(z3[2], w0.z, s3);
      s0 = fmaf(z0[3], w0.w, s0); s1 = fmaf(z1[3], w0.w, s1); s2 = fmaf(z2[3], w0.w, s2); s3 = fmaf(z3[3], w0.w, s3);
      s0 = fmaf(z0[4], w1.x, s0); s1 = fmaf(z1[4], w1.x, s1); s2 = fmaf(z2[4], w1.x, s2); s3 = fmaf(z3[4], w1.x, s3);
      s0 = fmaf(z0[5], w1.y, s0); s1 = fmaf(z1[5], w1.y, s1); s2 = fmaf(z2[5], w1.y, s2); s3 = fmaf(z3[5], w1.y, s3);
      s0 = fmaf(z0[6], w1.z, s0); s1 = fmaf(z1[6], w1.z, s1); s2 = fmaf(z2[6], w1.z, s2); s3 = fmaf(z3[6], w1.z, s3);
      s0 = fmaf(z0[7], w1.w, s0); s1 = fmaf(z1[7], w1.w, s1); s2 = fmaf(z2[7], w1.w, s2); s3 = fmaf(z3[7], w1.w, s3);
      *(float4*)&op[(size_t)o*TT] = make_float4(s0, s1, s2, s3);
    }
  }
}

// ---------------- finalize: losses (idempotent) ----------------
__global__ void vq_fin(const float* __restrict__ lpart, float* __restrict__ dout)
{
  const int b = threadIdx.x;
  if (b < NB) {
    float s = 0.f;
    for (int j = 0; j < NTA; ++j) s += lpart[b*NTA + j];
    const float v = s / (float)(TT*DC);
    dout[OFF_CL + b] = v;
    dout[OFF_CB + b] = v;
  }
}

extern "C" void kernel_launch(void* const* d_in, const int* in_sizes, int n_in,
                              void* d_out, int out_size, void* d_ws, size_t ws_size,
                              hipStream_t stream) {
  const float* z     = (const float*)d_in[0];
  const float* in_w  = (const float*)d_in[1];
  const float* in_b  = (const float*)d_in[2];
  const float* out_w = (const float*)d_in[3];
  const float* out_b = (const float*)d_in[4];
  const float* cbk   = (const float*)d_in[5];
  float* out = (float*)d_out;
  float* LP  = (float*)d_ws;   // NB*NTA = 512 floats

  vq_mega<<<dim3(NTA, NB), 512, 0, stream>>>(z, in_w, in_b, out_w, out_b, cbk, out, LP);
  vq_fin <<<1, 256, 0, stream>>>(LP, out);
}

// Round 13
// 136.913 us; speedup vs baseline: 1.2661x; 1.2661x over previous
//
#include <hip/hip_runtime.h>
#include <math.h>

#define NB   16
#define DIN  1024
#define TT   4096
#define DC   8
#define NK   1024
#define TA   128
#define NTA  (TT/TA)      // 32
#define NPG  16
#define KCP  (NK/NPG)     // 64

// d_out offsets (floats), in reference return order
#define OFF_CL  ((size_t)NB*DIN*TT)
#define OFF_CB  (OFF_CL + NB)
#define OFF_IDX (OFF_CB + NB)
#define OFF_ZE  (OFF_IDX + (size_t)NB*TT)

// ---------------- MEGA: in_proj -> VQ -> rotation -> out_proj, one block per (b, t-tile) ----------------
__global__ __launch_bounds__(512, 4) void vq_mega(const float* __restrict__ z,
    const float* __restrict__ in_w, const float* __restrict__ in_b,
    const float* __restrict__ out_w, const float* __restrict__ out_b,
    const float* __restrict__ cbk, float* __restrict__ dout,
    float* __restrict__ lpart)
{
  __shared__ float regA[DIN*DC];    // 32 KB: wt[d][o] -> cn[k][i] -> wo[o][c]
  __shared__ float regB[8*TA*DC];   // 32 KB: pacc[8][t][o]; then cand/cn2/obs/zq_s/lred
  __shared__ float ze_s[DC*TA];     //  4 KB [o][t]
  // aliases into regB (pacc dead after combine barrier):
  float2* cand = (float2*)regB;           // floats 0..4095   (16 pg x 128 t)
  float*  cn2  = regB + 4096;             // floats 4096..5119
  float*  obs  = regB + 5120;             // floats 5120..6143
  float*  zq_s = regB + 6144;             // floats 6144..7167 [c][t]
  float*  lred = regB + 7168;             // floats 7168..7295

  const int tid = threadIdx.x;
  const int tb = blockIdx.x, b = blockIdx.y;
  const int t0 = tb*TA;

  // ======== P1: in_proj — 8 d-subs x 64 lanes, 2 t/thread (float2); all 512 threads load ========
  for (int i = tid; i < DIN*DC; i += 512) {
    const int d = i >> 3, o = i & 7;
    regA[i] = in_w[o*DIN + d];
  }
  __syncthreads();
  {
    const int sub = tid >> 6, l = tid & 63;
    const int dbase = sub*128;
    const float* zp = z + ((size_t)b*DIN + dbase)*TT + t0 + 2*l;
    float ax[DC], ay[DC];
    #pragma unroll
    for (int o = 0; o < DC; ++o) { ax[o] = 0.f; ay[o] = 0.f; }
    #pragma unroll 8
    for (int d = 0; d < 128; ++d) {
      const float2 v = *(const float2*)&zp[(size_t)d*TT];
      const float4 w0 = *(const float4*)&regA[(dbase+d)*DC];
      const float4 w1 = *(const float4*)&regA[(dbase+d)*DC+4];
      ax[0] = fmaf(v.x, w0.x, ax[0]);  ay[0] = fmaf(v.y, w0.x, ay[0]);
      ax[1] = fmaf(v.x, w0.y, ax[1]);  ay[1] = fmaf(v.y, w0.y, ay[1]);
      ax[2] = fmaf(v.x, w0.z, ax[2]);  ay[2] = fmaf(v.y, w0.z, ay[2]);
      ax[3] = fmaf(v.x, w0.w, ax[3]);  ay[3] = fmaf(v.y, w0.w, ay[3]);
      ax[4] = fmaf(v.x, w1.x, ax[4]);  ay[4] = fmaf(v.y, w1.x, ay[4]);
      ax[5] = fmaf(v.x, w1.y, ax[5]);  ay[5] = fmaf(v.y, w1.y, ay[5]);
      ax[6] = fmaf(v.x, w1.z, ax[6]);  ay[6] = fmaf(v.y, w1.z, ay[6]);
      ax[7] = fmaf(v.x, w1.w, ax[7]);  ay[7] = fmaf(v.y, w1.w, ay[7]);
    }
    float* pa = &regB[((size_t)sub*TA + 2*l)*DC];   // pacc[sub][2l..2l+1][.]
    *(float4*)&pa[0]    = make_float4(ax[0], ax[1], ax[2], ax[3]);
    *(float4*)&pa[4]    = make_float4(ax[4], ax[5], ax[6], ax[7]);
    *(float4*)&pa[DC]   = make_float4(ay[0], ay[1], ay[2], ay[3]);
    *(float4*)&pa[DC+4] = make_float4(ay[4], ay[5], ay[6], ay[7]);
  }
  __syncthreads();
  // combine: ascending chunk order 0..7 (bit-identical to round-6 validated path)
  {
    const int t = tid & 127, oq = tid >> 7;     // oq 0..3 -> o pair (2oq, 2oq+1)
    const int o0 = 2*oq;
    float2 p = *(const float2*)&regB[(0*TA + t)*DC + o0];
    float s0 = p.x, s1 = p.y;
    #pragma unroll
    for (int c = 1; c < 8; ++c) {
      p = *(const float2*)&regB[(c*TA + t)*DC + o0];
      s0 += p.x; s1 += p.y;
    }
    const float v0 = s0 + in_b[o0];
    const float v1 = s1 + in_b[o0+1];
    ze_s[o0*TA + t]     = v0;
    ze_s[(o0+1)*TA + t] = v1;
    dout[OFF_ZE + ((size_t)b*DC + o0)*TT + t0 + t]     = v0;
    dout[OFF_ZE + ((size_t)b*DC + o0+1)*TT + t0 + t]   = v1;
  }
  __syncthreads();

  // ======== P2: stage+normalize codebook into regA (round-1 chain) ========
  for (int k = tid; k < NK; k += 512) {
    float c[DC];
    const float4 c0 = *(const float4*)&cbk[k*DC];
    const float4 c1 = *(const float4*)&cbk[k*DC+4];
    c[0]=c0.x; c[1]=c0.y; c[2]=c0.z; c[3]=c0.w;
    c[4]=c1.x; c[5]=c1.y; c[6]=c1.z; c[7]=c1.w;
    float ss = 0.f;
    #pragma unroll
    for (int i = 0; i < DC; ++i) ss = fmaf(c[i], c[i], ss);
    const float den = fmaxf(sqrtf(ss), 1e-12f);
    float s2 = 0.f;
    #pragma unroll
    for (int i = 0; i < DC; ++i) { const float v = c[i]/den; regA[k*DC+i] = v; s2 = fmaf(v, v, s2); }
    cn2[k] = s2;
  }
  __syncthreads();

  // scan: 16 partitions x 32 lanes, 4 t/thread (round-10 verbatim)
  {
    const int pg = tid >> 5, l = tid & 31;
    const int k0 = pg*KCP;
    float en[4][DC], en2v[4];
    #pragma unroll
    for (int m = 0; m < 4; ++m) {
      const int t = l + 32*m;
      float e[DC];
      #pragma unroll
      for (int o = 0; o < DC; ++o) e[o] = ze_s[o*TA + t];
      float se = 0.f;
      #pragma unroll
      for (int i = 0; i < DC; ++i) se = fmaf(e[i], e[i], se);
      const float dene = fmaxf(sqrtf(se), 1e-12f);
      float s2 = 0.f;
      #pragma unroll
      for (int i = 0; i < DC; ++i) { en[m][i] = e[i]/dene; s2 = fmaf(en[m][i], en[m][i], s2); }
      en2v[m] = s2;
    }
    float bd[4]; int bk[4];
    #pragma unroll
    for (int m = 0; m < 4; ++m) { bd[m] = 3.4e38f; bk[m] = k0; }
    #pragma unroll 2
    for (int k = 0; k < KCP; ++k) {
      const float4 a0 = *(const float4*)&regA[(k0+k)*DC];
      const float4 a1 = *(const float4*)&regA[(k0+k)*DC+4];
      const float c2 = cn2[k0+k];
      #pragma unroll
      for (int m = 0; m < 4; ++m) {
        float dacc = en[m][0]*a0.x;
        dacc = fmaf(en[m][1], a0.y, dacc);
        dacc = fmaf(en[m][2], a0.z, dacc);
        dacc = fmaf(en[m][3], a0.w, dacc);
        dacc = fmaf(en[m][4], a1.x, dacc);
        dacc = fmaf(en[m][5], a1.y, dacc);
        dacc = fmaf(en[m][6], a1.z, dacc);
        dacc = fmaf(en[m][7], a1.w, dacc);
        const float dist = (en2v[m] - 2.0f*dacc) + c2;   // exact round-1 chain
        if (dist < bd[m]) { bd[m] = dist; bk[m] = k0 + k; }
      }
    }
    #pragma unroll
    for (int m = 0; m < 4; ++m)
      cand[pg*TA + l + 32*m] = make_float2(bd[m], __int_as_float(bk[m]));
  }
  __syncthreads();

  // merge + rotation (lanes < 128) overlapped with out_w staging (lanes >= 128)
  if (tid < TA) {
    float bdm = cand[tid].x;
    int bkm = __float_as_int(cand[tid].y);
    #pragma unroll
    for (int p = 1; p < NPG; ++p) {
      const float2 c = cand[p*TA + tid];
      if (c.x < bdm) { bdm = c.x; bkm = __float_as_int(c.y); }   // ascending p => first occurrence
    }
    dout[OFF_IDX + (size_t)b*TT + t0 + tid] = (float)bkm;

    float e[DC], en_[DC];
    #pragma unroll
    for (int o = 0; o < DC; ++o) e[o] = ze_s[o*TA + tid];
    float se = 0.f;
    #pragma unroll
    for (int i = 0; i < DC; ++i) se = fmaf(e[i], e[i], se);
    const float ne = sqrtf(se);
    const float dene = fmaxf(ne, 1e-12f);
    #pragma unroll
    for (int i = 0; i < DC; ++i) en_[i] = e[i]/dene;

    float q[DC];
    {
      const float4 q0 = *(const float4*)&cbk[bkm*DC];
      const float4 q1 = *(const float4*)&cbk[bkm*DC+4];
      q[0]=q0.x; q[1]=q0.y; q[2]=q0.z; q[3]=q0.w;
      q[4]=q1.x; q[5]=q1.y; q[6]=q1.z; q[7]=q1.w;
    }
    float cl = 0.f;
    #pragma unroll
    for (int i = 0; i < DC; ++i) { const float d = e[i]-q[i]; cl = fmaf(d, d, cl); }

    float sq = 0.f;
    #pragma unroll
    for (int i = 0; i < DC; ++i) sq = fmaf(q[i], q[i], sq);
    const float nq = sqrtf(sq);
    const float denq = fmaxf(nq, 1e-12f);
    float qn[DC], rr[DC];
    float sr = 0.f;
    #pragma unroll
    for (int i = 0; i < DC; ++i) { qn[i] = q[i]/denq; rr[i] = en_[i]+qn[i]; sr = fmaf(rr[i], rr[i], sr); }
    const float denr = fmaxf(sqrtf(sr), 1e-12f);
    float r_[DC];
    float rdz = 0.f, edz = 0.f;
    #pragma unroll
    for (int i = 0; i < DC; ++i) { r_[i] = rr[i]/denr; rdz = fmaf(r_[i], e[i], rdz); edz = fmaf(en_[i], e[i], edz); }
    const float scal = nq / fmaxf(ne, 1e-8f);
    #pragma unroll
    for (int i = 0; i < DC; ++i) {
      const float v = scal * ((e[i] - 2.0f*r_[i]*rdz) + 2.0f*qn[i]*edz);
      zq_s[i*TA + tid] = v;
    }
    lred[tid] = cl;
  } else {
    const int ti = tid - TA;   // 384 stagers
    for (int i = ti; i < DIN*DC; i += 512-TA) regA[i] = out_w[i];
    for (int i = ti; i < DIN; i += 512-TA) obs[i] = out_b[i];
  }
  __syncthreads();
  for (int s = TA/2; s > 0; s >>= 1) {
    if (tid < s) lred[tid] += lred[tid + s];
    __syncthreads();
  }
  if (tid == 0) lpart[b*NTA + tb] = lred[0];

  // ======== P3: out_proj (round-10 verbatim: 8 groups x 64 lanes, wave-uniform weight reads) ========
  {
    const int sub3 = tid >> 6, tl2 = tid & 63;
    const int obase = sub3*128;
    const int tt2 = tl2*2;
    float zx[DC], zy[DC];
    #pragma unroll
    for (int c = 0; c < DC; ++c) {
      zx[c] = zq_s[c*TA + tt2];
      zy[c] = zq_s[c*TA + tt2 + 1];
    }
    float* op = dout + ((size_t)b*DIN + obase)*TT + t0 + tt2;
    #pragma unroll 4
    for (int o = 0; o < 128; ++o) {
      const float4 w0 = *(const float4*)&regA[(obase+o)*DC];
      const float4 w1 = *(const float4*)&regA[(obase+o)*DC+4];
      const float bv = obs[obase+o];
      float s0 = bv, s1 = bv;
      s0 = fmaf(zx[0], w0.x, s0);  s1 = fmaf(zy[0], w0.x, s1);
      s0 = fmaf(zx[1], w0.y, s0);  s1 = fmaf(zy[1], w0.y, s1);
      s0 = fmaf(zx[2], w0.z, s0);  s1 = fmaf(zy[2], w0.z, s1);
      s0 = fmaf(zx[3], w0.w, s0);  s1 = fmaf(zy[3], w0.w, s1);
      s0 = fmaf(zx[4], w1.x, s0);  s1 = fmaf(zy[4], w1.x, s1);
      s0 = fmaf(zx[5], w1.y, s0);  s1 = fmaf(zy[5], w1.y, s1);
      s0 = fmaf(zx[6], w1.z, s0);  s1 = fmaf(zy[6], w1.z, s1);
      s0 = fmaf(zx[7], w1.w, s0);  s1 = fmaf(zy[7], w1.w, s1);
      *(float2*)&op[(size_t)o*TT] = make_float2(s0, s1);
    }
  }
}

// ---------------- finalize: losses (idempotent) ----------------
__global__ void vq_fin(const float* __restrict__ lpart, float* __restrict__ dout)
{
  const int b = threadIdx.x;
  if (b < NB) {
    float s = 0.f;
    for (int j = 0; j < NTA; ++j) s += lpart[b*NTA + j];
    const float v = s / (float)(TT*DC);
    dout[OFF_CL + b] = v;
    dout[OFF_CB + b] = v;
  }
}

extern "C" void kernel_launch(void* const* d_in, const int* in_sizes, int n_in,
                              void* d_out, int out_size, void* d_ws, size_t ws_size,
                              hipStream_t stream) {
  const float* z     = (const float*)d_in[0];
  const float* in_w  = (const float*)d_in[1];
  const float* in_b  = (const float*)d_in[2];
  const float* out_w = (const float*)d_in[3];
  const float* out_b = (const float*)d_in[4];
  const float* cbk   = (const float*)d_in[5];
  float* out = (float*)d_out;
  float* LP  = (float*)d_ws;   // NB*NTA = 512 floats

  vq_mega<<<dim3(NTA, NB), 512, 0, stream>>>(z, in_w, in_b, out_w, out_b, cbk, out, LP);
  vq_fin <<<1, 256, 0, stream>>>(LP, out);
}